// Round 1
// baseline (9029.716 us; speedup 1.0000x reference)
//
#include <hip/hip_runtime.h>
#include <math.h>

#define NN 100000
#define NE 1600000
#define H 150
#define NG 256
#define NL 5
#define GH 200
#define RS 152   // padded LDS row stride in floats (152*4 % 16 == 0)

__device__ __forceinline__ float sigf(float x){ return 1.0f/(1.0f+expf(-x)); }

// transpose w_ih,w_hh: (450,150) row-major -> (150,450) row-major
__global__ void k_transpose(const float* __restrict__ wih, const float* __restrict__ whh,
                            float* __restrict__ wihT, float* __restrict__ whhT){
  int idx = blockIdx.x*256 + threadIdx.x;
  if (idx < 450*H){
    int k = idx / 450, j = idx - k*450;
    wihT[idx] = wih[j*H + k];
    whhT[idx] = whh[j*H + k];
  }
}

// m[N,150] = h[N,150] @ W[150,150]
__global__ __launch_bounds__(256) void k_matmul(const float* __restrict__ h,
        const float* __restrict__ W, float* __restrict__ m){
  __shared__ float hs[32*RS];
  const int tid = threadIdx.x;
  const int row0 = blockIdx.x * 32;
  for (int i = tid; i < 32*H; i += 256){
    int r = i/H, k = i - r*H;
    hs[r*RS+k] = h[(size_t)(row0+r)*H + k];
  }
  __syncthreads();
  const int lane = tid & 63;
  const int r0 = (tid >> 6) * 8;
  const int c0 = lane, c1 = lane+64, c2 = lane+128;
  const bool v2 = (c2 < H);
  float acc0[8], acc1[8], acc2[8];
  #pragma unroll
  for (int i=0;i<8;i++){ acc0[i]=0.f; acc1[i]=0.f; acc2[i]=0.f; }
  for (int k=0;k<H;k+=2){
    const float* Wk = W + (size_t)k*H;
    float w00 = Wk[c0],   w10 = Wk[c1];
    float w01 = Wk[H+c0], w11 = Wk[H+c1];
    float w20 = v2?Wk[c2]:0.f, w21 = v2?Wk[H+c2]:0.f;
    #pragma unroll
    for (int i=0;i<8;i++){
      float2 a = *(const float2*)&hs[(r0+i)*RS + k];
      acc0[i] = fmaf(a.y, w01, fmaf(a.x, w00, acc0[i]));
      acc1[i] = fmaf(a.y, w11, fmaf(a.x, w10, acc1[i]));
      acc2[i] = fmaf(a.y, w21, fmaf(a.x, w20, acc2[i]));
    }
  }
  #pragma unroll
  for (int i=0;i<8;i++){
    size_t base = (size_t)(row0 + r0 + i)*H;
    m[base+c0] = acc0[i];
    m[base+c1] = acc1[i];
    if (v2) m[base+c2] = acc2[i];
  }
}

// agg[dst] += m[src], one wave per edge
__global__ __launch_bounds__(256) void k_scatter(const float* __restrict__ m,
        const int* __restrict__ es, const int* __restrict__ ed, float* __restrict__ agg){
  const int lane = threadIdx.x & 63;
  const int e = blockIdx.x*4 + (threadIdx.x>>6);
  if (e >= NE) return;
  const int s = es[e], d = ed[e];
  const float* mr = m + (size_t)s*H;
  float* ar = agg + (size_t)d*H;
  atomicAdd(&ar[lane],     mr[lane]);
  atomicAdd(&ar[lane+64],  mr[lane+64]);
  if (lane < H-128) atomicAdd(&ar[lane+128], mr[lane+128]);
}

// fused GRU: h = GRU(agg, h) in place
__global__ __launch_bounds__(256) void k_gru(const float* __restrict__ agg,
        float* __restrict__ h, const float* __restrict__ wihT, const float* __restrict__ whhT,
        const float* __restrict__ bih, const float* __restrict__ bhh){
  __shared__ float as_[32*RS];
  __shared__ float hs[32*RS];
  const int tid = threadIdx.x;
  const int row0 = blockIdx.x*32;
  for (int i = tid; i < 32*H; i += 256){
    int r = i/H, k = i - r*H;
    size_t gidx = (size_t)(row0+r)*H + k;
    as_[r*RS+k] = agg[gidx];
    hs[r*RS+k]  = h[gidx];
  }
  __syncthreads();
  const int lane = tid & 63;
  const int r0 = (tid>>6)*8;
  const int c0=lane, c1=lane+64, c2=lane+128;
  const bool v2 = (c2 < H);
  float rv0[8],rv1[8],rv2[8], zv0[8],zv1[8],zv2[8];
  #pragma unroll 1
  for (int g=0; g<3; ++g){
    float ai0[8],ai1[8],ai2[8],ah0[8],ah1[8],ah2[8];
    const float* wi = wihT + g*H;   // [k*450 + c]
    const float* wh = whhT + g*H;
    float bi0 = bih[g*H+c0], bi1 = bih[g*H+c1], bi2 = v2?bih[g*H+c2]:0.f;
    float bh0 = bhh[g*H+c0], bh1 = bhh[g*H+c1], bh2 = v2?bhh[g*H+c2]:0.f;
    #pragma unroll
    for (int i=0;i<8;i++){ ai0[i]=bi0; ai1[i]=bi1; ai2[i]=bi2;
                           ah0[i]=bh0; ah1[i]=bh1; ah2[i]=bh2; }
    for (int k=0;k<H;k+=2){
      const float* wik = wi + (size_t)k*450;
      const float* whk = wh + (size_t)k*450;
      float wi00=wik[c0], wi10=wik[c1];
      float wi01=wik[450+c0], wi11=wik[450+c1];
      float wh00=whk[c0], wh10=whk[c1];
      float wh01=whk[450+c0], wh11=whk[450+c1];
      float wi20=v2?wik[c2]:0.f, wi21=v2?wik[450+c2]:0.f;
      float wh20=v2?whk[c2]:0.f, wh21=v2?whk[450+c2]:0.f;
      #pragma unroll
      for (int i=0;i<8;i++){
        float2 a  = *(const float2*)&as_[(r0+i)*RS+k];
        float2 hh = *(const float2*)&hs[(r0+i)*RS+k];
        ai0[i]=fmaf(a.y,wi01,fmaf(a.x,wi00,ai0[i]));
        ai1[i]=fmaf(a.y,wi11,fmaf(a.x,wi10,ai1[i]));
        ai2[i]=fmaf(a.y,wi21,fmaf(a.x,wi20,ai2[i]));
        ah0[i]=fmaf(hh.y,wh01,fmaf(hh.x,wh00,ah0[i]));
        ah1[i]=fmaf(hh.y,wh11,fmaf(hh.x,wh10,ah1[i]));
        ah2[i]=fmaf(hh.y,wh21,fmaf(hh.x,wh20,ah2[i]));
      }
    }
    if (g==0){
      #pragma unroll
      for (int i=0;i<8;i++){ rv0[i]=sigf(ai0[i]+ah0[i]); rv1[i]=sigf(ai1[i]+ah1[i]); rv2[i]=sigf(ai2[i]+ah2[i]); }
    } else if (g==1){
      #pragma unroll
      for (int i=0;i<8;i++){ zv0[i]=sigf(ai0[i]+ah0[i]); zv1[i]=sigf(ai1[i]+ah1[i]); zv2[i]=sigf(ai2[i]+ah2[i]); }
    } else {
      #pragma unroll
      for (int i=0;i<8;i++){
        float n0 = tanhf(ai0[i] + rv0[i]*ah0[i]);
        float n1 = tanhf(ai1[i] + rv1[i]*ah1[i]);
        float n2 = tanhf(ai2[i] + rv2[i]*ah2[i]);
        size_t base = (size_t)(row0+r0+i)*H;
        float h0 = hs[(r0+i)*RS+c0];
        float h1 = hs[(r0+i)*RS+c1];
        h[base+c0] = (1.f-zv0[i])*n0 + zv0[i]*h0;
        h[base+c1] = (1.f-zv1[i])*n1 + zv1[i]*h1;
        if (v2){
          float h2 = hs[(r0+i)*RS+c2];
          h[base+c2] = (1.f-zv2[i])*n2 + zv2[i]*h2;
        }
      }
    }
  }
}

// gate_pre[n] = tanh(h[n]@gw1 + gb1) @ gw2 + gb2
__global__ __launch_bounds__(256) void k_gatepre(const float* __restrict__ h,
      const float* __restrict__ gw1, const float* __restrict__ gb1,
      const float* __restrict__ gw2, const float* __restrict__ gb2,
      float* __restrict__ gatebuf){
  __shared__ float hs[32*RS];
  const int tid = threadIdx.x;
  const int row0 = blockIdx.x*32;
  for (int i = tid; i < 32*H; i += 256){
    int r = i/H, k = i - r*H;
    hs[r*RS+k] = h[(size_t)(row0+r)*H + k];
  }
  __syncthreads();
  const int lane = tid&63;
  const int r0 = (tid>>6)*8;
  const int c0=lane, c1=lane+64, c2=lane+128, c3=lane+192;
  const bool v3 = (c3 < GH);
  float g20 = gw2[c0], g21 = gw2[c1], g22 = gw2[c2], g23 = v3?gw2[c3]:0.f;
  float a0[8],a1[8],a2[8],a3[8];
  float b0 = gb1[c0], b1 = gb1[c1], b2 = gb1[c2], b3 = v3?gb1[c3]:0.f;
  #pragma unroll
  for (int i=0;i<8;i++){ a0[i]=b0; a1[i]=b1; a2[i]=b2; a3[i]=b3; }
  for (int k=0;k<H;k+=2){
    const float* wk = gw1 + (size_t)k*GH;
    float w00=wk[c0], w10=wk[c1], w20=wk[c2], w30=v3?wk[c3]:0.f;
    float w01=wk[GH+c0], w11=wk[GH+c1], w21=wk[GH+c2], w31=v3?wk[GH+c3]:0.f;
    #pragma unroll
    for (int i=0;i<8;i++){
      float2 a = *(const float2*)&hs[(r0+i)*RS + k];
      a0[i]=fmaf(a.y,w01,fmaf(a.x,w00,a0[i]));
      a1[i]=fmaf(a.y,w11,fmaf(a.x,w10,a1[i]));
      a2[i]=fmaf(a.y,w21,fmaf(a.x,w20,a2[i]));
      a3[i]=fmaf(a.y,w31,fmaf(a.x,w30,a3[i]));
    }
  }
  float gb2v = gb2[0];
  #pragma unroll
  for (int i=0;i<8;i++){
    float p = tanhf(a0[i])*g20 + tanhf(a1[i])*g21 + tanhf(a2[i])*g22 + tanhf(a3[i])*g23;
    #pragma unroll
    for (int off=32; off>=1; off>>=1) p += __shfl_xor(p, off);
    if (lane==0) gatebuf[row0+r0+i] = p + gb2v;
  }
}

// per-graph segment softmax + weighted sum (batch sorted)
__global__ __launch_bounds__(256) void k_readout(float* __restrict__ gatebuf,
    const float* __restrict__ h, const int* __restrict__ batch,
    float* __restrict__ out, float* __restrict__ gate_out){
  const int g = blockIdx.x;
  const int tid = threadIdx.x;
  // lower_bound for g and g+1
  int lo=0, hi=NN;
  while (lo<hi){ int mid=(lo+hi)>>1; if (batch[mid] < g) lo=mid+1; else hi=mid; }
  const int start = lo;
  hi = NN;
  while (lo<hi){ int mid=(lo+hi)>>1; if (batch[mid] < g+1) lo=mid+1; else hi=mid; }
  const int end = lo;

  __shared__ float red[256];
  __shared__ float s_max, s_inv;
  float mx = -INFINITY;
  for (int n = start+tid; n < end; n += 256) mx = fmaxf(mx, gatebuf[n]);
  red[tid]=mx; __syncthreads();
  for (int s=128; s>=1; s>>=1){ if (tid<s) red[tid]=fmaxf(red[tid],red[tid+s]); __syncthreads(); }
  if (tid==0) s_max = red[0];
  __syncthreads();
  const float gmax = s_max;
  float sum = 0.f;
  for (int n = start+tid; n < end; n += 256){
    float e = expf(gatebuf[n]-gmax);
    gatebuf[n] = e;
    sum += e;
  }
  red[tid]=sum; __syncthreads();
  for (int s=128; s>=1; s>>=1){ if (tid<s) red[tid]+=red[tid+s]; __syncthreads(); }
  if (tid==0) s_inv = 1.0f/(red[0] + 1e-16f);
  __syncthreads();
  const float inv = s_inv;
  for (int n = start+tid; n < end; n += 256) gate_out[n] = gatebuf[n]*inv;
  if (tid < H){
    float acc = 0.f;
    for (int n = start; n < end; ++n)
      acc = fmaf(gatebuf[n], h[(size_t)n*H + tid], acc);
    out[g*H + tid] = acc*inv;
  }
}

extern "C" void kernel_launch(void* const* d_in, const int* in_sizes, int n_in,
                              void* d_out, int out_size, void* d_ws, size_t ws_size,
                              hipStream_t stream) {
  (void)in_sizes; (void)n_in; (void)out_size; (void)ws_size;
  const float* x    = (const float*)d_in[0];
  const int*   eidx = (const int*)d_in[1];   // [2,E]: src=eidx[0..E), dst=eidx[E..2E)
  const int*   batch= (const int*)d_in[2];
  const float* W    = (const float*)d_in[3]; // [L,H,H]
  const float* wih  = (const float*)d_in[4]; // [3H,H]
  const float* whh  = (const float*)d_in[5];
  const float* bih  = (const float*)d_in[6];
  const float* bhh  = (const float*)d_in[7];
  const float* gw1  = (const float*)d_in[8]; // [H,GH]
  const float* gb1  = (const float*)d_in[9];
  const float* gw2  = (const float*)d_in[10];// [GH,1]
  const float* gb2  = (const float*)d_in[11];

  float* out      = (float*)d_out;           // [NG*H]
  float* gate_out = out + NG*H;              // [NN]

  float* ws   = (float*)d_ws;
  float* h    = ws;
  float* m    = h   + (size_t)NN*H;
  float* agg  = m   + (size_t)NN*H;
  float* gbuf = agg + (size_t)NN*H;
  float* wihT = gbuf + NN;
  float* whhT = wihT + 450*H;

  hipMemcpyAsync(h, x, sizeof(float)*(size_t)NN*H, hipMemcpyDeviceToDevice, stream);
  k_transpose<<<(450*H + 255)/256, 256, 0, stream>>>(wih, whh, wihT, whhT);

  for (int l = 0; l < NL; ++l){
    k_matmul<<<NN/32, 256, 0, stream>>>(h, W + (size_t)l*H*H, m);
    hipMemsetAsync(agg, 0, sizeof(float)*(size_t)NN*H, stream);
    k_scatter<<<NE/4, 256, 0, stream>>>(m, eidx, eidx + NE, agg);
    k_gru<<<NN/32, 256, 0, stream>>>(agg, h, wihT, whhT, bih, bhh);
  }
  k_gatepre<<<NN/32, 256, 0, stream>>>(h, gw1, gb1, gw2, gb2, gbuf);
  k_readout<<<NG, 256, 0, stream>>>(gbuf, h, batch, out, gate_out);
}

// Round 2
// 4762.515 us; speedup vs baseline: 1.8960x; 1.8960x over previous
//
#include <hip/hip_runtime.h>
#include <math.h>

#define NN 100000
#define NE 1600000
#define H 150
#define NG 256
#define NL 5
#define GH 200
#define RS 152   // padded LDS row stride in floats

__device__ __forceinline__ float sigf(float x){ return 1.0f/(1.0f+expf(-x)); }

// ---- CSR build ----
__global__ void k_hist(const int* __restrict__ ed, int* __restrict__ cnt){
  int e = blockIdx.x*256 + threadIdx.x;
  if (e < NE) atomicAdd(&cnt[ed[e]], 1);
}

__global__ __launch_bounds__(1024) void k_scan(const int* __restrict__ cnt,
        int* __restrict__ rowptr, int* __restrict__ cursor){
  __shared__ int tmp[1024];
  __shared__ int carry_s;
  const int tid = threadIdx.x;
  if (tid == 0){ carry_s = 0; rowptr[0] = 0; }
  __syncthreads();
  for (int base = 0; base < NN; base += 1024){
    int i = base + tid;
    int v = (i < NN) ? cnt[i] : 0;
    tmp[tid] = v;
    __syncthreads();
    for (int off = 1; off < 1024; off <<= 1){
      int t = (tid >= off) ? tmp[tid - off] : 0;
      __syncthreads();
      tmp[tid] += t;
      __syncthreads();
    }
    int carry = carry_s;
    if (i < NN){
      int incl = carry + tmp[tid];
      rowptr[i+1] = incl;
      cursor[i]   = incl - v;   // exclusive prefix
    }
    __syncthreads();
    if (tid == 1023) carry_s = carry + tmp[1023];
    __syncthreads();
  }
}

__global__ void k_fill(const int* __restrict__ es, const int* __restrict__ ed,
                       int* __restrict__ cursor, int* __restrict__ csr){
  int e = blockIdx.x*256 + threadIdx.x;
  if (e < NE){
    int pos = atomicAdd(&cursor[ed[e]], 1);
    csr[pos] = es[e];
  }
}

// ---- weight prep ----
// whhT[k*450 + j] = whh[j*150 + k]
__global__ void k_transpose(const float* __restrict__ whh, float* __restrict__ whhT){
  int idx = blockIdx.x*256 + threadIdx.x;
  if (idx < 450*H){
    int k = idx / 450, j = idx - k*450;
    whhT[idx] = whh[j*H + k];
  }
}

// Wc[l][k*450 + j] = sum_t W[l][k][t] * wih[j][t]   (= (W[l] @ w_ih^T))
__global__ __launch_bounds__(256) void k_wc(const float* __restrict__ W,
        const float* __restrict__ wih, float* __restrict__ Wc){
  int idx = blockIdx.x*256 + threadIdx.x;
  if (idx >= NL*H*450) return;
  int l = idx / (H*450);
  int rem = idx - l*H*450;
  int k = rem / 450;
  int j = rem - k*450;
  const float* Wr = W   + (size_t)l*H*H + (size_t)k*H;
  const float* wr = wih + (size_t)j*H;
  float acc = 0.f;
  for (int t = 0; t < H; ++t) acc = fmaf(Wr[t], wr[t], acc);
  Wc[idx] = acc;
}

// ---- per-layer: aggH[n] = sum_{e: dst==n} h[src[e]] ----
__global__ __launch_bounds__(256) void k_gather(const float* __restrict__ h,
        const int* __restrict__ rowptr, const int* __restrict__ csr,
        float* __restrict__ agg){
  const int lane = threadIdx.x & 63;
  const int n = blockIdx.x*4 + (threadIdx.x >> 6);
  if (n >= NN) return;
  const int s0 = rowptr[n], s1 = rowptr[n+1];
  const bool v2 = lane < (H - 128);
  float a0 = 0.f, a1 = 0.f, a2 = 0.f;
  int j = s0;
  for (; j + 1 < s1; j += 2){
    const float* r0 = h + (size_t)csr[j]*H;
    const float* r1 = h + (size_t)csr[j+1]*H;
    float x0 = r0[lane], x1 = r0[lane+64], x2 = v2 ? r0[lane+128] : 0.f;
    float y0 = r1[lane], y1 = r1[lane+64], y2 = v2 ? r1[lane+128] : 0.f;
    a0 += x0 + y0; a1 += x1 + y1; a2 += x2 + y2;
  }
  if (j < s1){
    const float* r0 = h + (size_t)csr[j]*H;
    a0 += r0[lane]; a1 += r0[lane+64]; if (v2) a2 += r0[lane+128];
  }
  float* ar = agg + (size_t)n*H;
  ar[lane] = a0; ar[lane+64] = a1; if (v2) ar[lane+128] = a2;
}

// ---- fused GRU: h = GRU(aggH@Wc (+b_ih), h@whh^T (+b_hh)) in place ----
__global__ __launch_bounds__(256) void k_gru(const float* __restrict__ agg,
        float* __restrict__ h, const float* __restrict__ Wcl, const float* __restrict__ whhT,
        const float* __restrict__ bih, const float* __restrict__ bhh){
  __shared__ float as_[32*RS];
  __shared__ float hs[32*RS];
  const int tid = threadIdx.x;
  const int row0 = blockIdx.x*32;
  for (int i = tid; i < 32*H; i += 256){
    int r = i/H, k = i - r*H;
    size_t gidx = (size_t)(row0+r)*H + k;
    as_[r*RS+k] = agg[gidx];
    hs[r*RS+k]  = h[gidx];
  }
  __syncthreads();
  const int lane = tid & 63;
  const int r0 = (tid>>6)*8;
  const int c0=lane, c1=lane+64, c2=lane+128;
  const bool v2 = (c2 < H);
  float rv0[8],rv1[8],rv2[8], zv0[8],zv1[8],zv2[8];
  #pragma unroll 1
  for (int g=0; g<3; ++g){
    float ai0[8],ai1[8],ai2[8],ah0[8],ah1[8],ah2[8];
    const float* wi = Wcl + g*H;    // [k*450 + c]
    const float* wh = whhT + g*H;
    float bi0 = bih[g*H+c0], bi1 = bih[g*H+c1], bi2 = v2?bih[g*H+c2]:0.f;
    float bh0 = bhh[g*H+c0], bh1 = bhh[g*H+c1], bh2 = v2?bhh[g*H+c2]:0.f;
    #pragma unroll
    for (int i=0;i<8;i++){ ai0[i]=bi0; ai1[i]=bi1; ai2[i]=bi2;
                           ah0[i]=bh0; ah1[i]=bh1; ah2[i]=bh2; }
    for (int k=0;k<H;k+=2){
      const float* wik = wi + (size_t)k*450;
      const float* whk = wh + (size_t)k*450;
      float wi00=wik[c0], wi10=wik[c1];
      float wi01=wik[450+c0], wi11=wik[450+c1];
      float wh00=whk[c0], wh10=whk[c1];
      float wh01=whk[450+c0], wh11=whk[450+c1];
      float wi20=v2?wik[c2]:0.f, wi21=v2?wik[450+c2]:0.f;
      float wh20=v2?whk[c2]:0.f, wh21=v2?whk[450+c2]:0.f;
      #pragma unroll
      for (int i=0;i<8;i++){
        float2 a  = *(const float2*)&as_[(r0+i)*RS+k];
        float2 hh = *(const float2*)&hs[(r0+i)*RS+k];
        ai0[i]=fmaf(a.y,wi01,fmaf(a.x,wi00,ai0[i]));
        ai1[i]=fmaf(a.y,wi11,fmaf(a.x,wi10,ai1[i]));
        ai2[i]=fmaf(a.y,wi21,fmaf(a.x,wi20,ai2[i]));
        ah0[i]=fmaf(hh.y,wh01,fmaf(hh.x,wh00,ah0[i]));
        ah1[i]=fmaf(hh.y,wh11,fmaf(hh.x,wh10,ah1[i]));
        ah2[i]=fmaf(hh.y,wh21,fmaf(hh.x,wh20,ah2[i]));
      }
    }
    if (g==0){
      #pragma unroll
      for (int i=0;i<8;i++){ rv0[i]=sigf(ai0[i]+ah0[i]); rv1[i]=sigf(ai1[i]+ah1[i]); rv2[i]=sigf(ai2[i]+ah2[i]); }
    } else if (g==1){
      #pragma unroll
      for (int i=0;i<8;i++){ zv0[i]=sigf(ai0[i]+ah0[i]); zv1[i]=sigf(ai1[i]+ah1[i]); zv2[i]=sigf(ai2[i]+ah2[i]); }
    } else {
      #pragma unroll
      for (int i=0;i<8;i++){
        float n0 = tanhf(ai0[i] + rv0[i]*ah0[i]);
        float n1 = tanhf(ai1[i] + rv1[i]*ah1[i]);
        float n2 = tanhf(ai2[i] + rv2[i]*ah2[i]);
        size_t base = (size_t)(row0+r0+i)*H;
        float h0 = hs[(r0+i)*RS+c0];
        float h1 = hs[(r0+i)*RS+c1];
        h[base+c0] = (1.f-zv0[i])*n0 + zv0[i]*h0;
        h[base+c1] = (1.f-zv1[i])*n1 + zv1[i]*h1;
        if (v2){
          float h2 = hs[(r0+i)*RS+c2];
          h[base+c2] = (1.f-zv2[i])*n2 + zv2[i]*h2;
        }
      }
    }
  }
}

// gate_pre[n] = tanh(h[n]@gw1 + gb1) @ gw2 + gb2
__global__ __launch_bounds__(256) void k_gatepre(const float* __restrict__ h,
      const float* __restrict__ gw1, const float* __restrict__ gb1,
      const float* __restrict__ gw2, const float* __restrict__ gb2,
      float* __restrict__ gatebuf){
  __shared__ float hs[32*RS];
  const int tid = threadIdx.x;
  const int row0 = blockIdx.x*32;
  for (int i = tid; i < 32*H; i += 256){
    int r = i/H, k = i - r*H;
    hs[r*RS+k] = h[(size_t)(row0+r)*H + k];
  }
  __syncthreads();
  const int lane = tid&63;
  const int r0 = (tid>>6)*8;
  const int c0=lane, c1=lane+64, c2=lane+128, c3=lane+192;
  const bool v3 = (c3 < GH);
  float g20 = gw2[c0], g21 = gw2[c1], g22 = gw2[c2], g23 = v3?gw2[c3]:0.f;
  float a0[8],a1[8],a2[8],a3[8];
  float b0 = gb1[c0], b1 = gb1[c1], b2 = gb1[c2], b3 = v3?gb1[c3]:0.f;
  #pragma unroll
  for (int i=0;i<8;i++){ a0[i]=b0; a1[i]=b1; a2[i]=b2; a3[i]=b3; }
  for (int k=0;k<H;k+=2){
    const float* wk = gw1 + (size_t)k*GH;
    float w00=wk[c0], w10=wk[c1], w20=wk[c2], w30=v3?wk[c3]:0.f;
    float w01=wk[GH+c0], w11=wk[GH+c1], w21=wk[GH+c2], w31=v3?wk[GH+c3]:0.f;
    #pragma unroll
    for (int i=0;i<8;i++){
      float2 a = *(const float2*)&hs[(r0+i)*RS + k];
      a0[i]=fmaf(a.y,w01,fmaf(a.x,w00,a0[i]));
      a1[i]=fmaf(a.y,w11,fmaf(a.x,w10,a1[i]));
      a2[i]=fmaf(a.y,w21,fmaf(a.x,w20,a2[i]));
      a3[i]=fmaf(a.y,w31,fmaf(a.x,w30,a3[i]));
    }
  }
  float gb2v = gb2[0];
  #pragma unroll
  for (int i=0;i<8;i++){
    float p = tanhf(a0[i])*g20 + tanhf(a1[i])*g21 + tanhf(a2[i])*g22 + tanhf(a3[i])*g23;
    #pragma unroll
    for (int off=32; off>=1; off>>=1) p += __shfl_xor(p, off);
    if (lane==0) gatebuf[row0+r0+i] = p + gb2v;
  }
}

// per-graph segment softmax + weighted sum (batch sorted)
__global__ __launch_bounds__(256) void k_readout(float* __restrict__ gatebuf,
    const float* __restrict__ h, const int* __restrict__ batch,
    float* __restrict__ out, float* __restrict__ gate_out){
  const int g = blockIdx.x;
  const int tid = threadIdx.x;
  int lo=0, hi=NN;
  while (lo<hi){ int mid=(lo+hi)>>1; if (batch[mid] < g) lo=mid+1; else hi=mid; }
  const int start = lo;
  hi = NN;
  while (lo<hi){ int mid=(lo+hi)>>1; if (batch[mid] < g+1) lo=mid+1; else hi=mid; }
  const int end = lo;

  __shared__ float red[256];
  __shared__ float s_max, s_inv;
  float mx = -INFINITY;
  for (int n = start+tid; n < end; n += 256) mx = fmaxf(mx, gatebuf[n]);
  red[tid]=mx; __syncthreads();
  for (int s=128; s>=1; s>>=1){ if (tid<s) red[tid]=fmaxf(red[tid],red[tid+s]); __syncthreads(); }
  if (tid==0) s_max = red[0];
  __syncthreads();
  const float gmax = s_max;
  float sum = 0.f;
  for (int n = start+tid; n < end; n += 256){
    float e = expf(gatebuf[n]-gmax);
    gatebuf[n] = e;
    sum += e;
  }
  red[tid]=sum; __syncthreads();
  for (int s=128; s>=1; s>>=1){ if (tid<s) red[tid]+=red[tid+s]; __syncthreads(); }
  if (tid==0) s_inv = 1.0f/(red[0] + 1e-16f);
  __syncthreads();
  const float inv = s_inv;
  for (int n = start+tid; n < end; n += 256) gate_out[n] = gatebuf[n]*inv;
  if (tid < H){
    float acc = 0.f;
    for (int n = start; n < end; ++n)
      acc = fmaf(gatebuf[n], h[(size_t)n*H + tid], acc);
    out[g*H + tid] = acc*inv;
  }
}

extern "C" void kernel_launch(void* const* d_in, const int* in_sizes, int n_in,
                              void* d_out, int out_size, void* d_ws, size_t ws_size,
                              hipStream_t stream) {
  (void)in_sizes; (void)n_in; (void)out_size; (void)ws_size;
  const float* x    = (const float*)d_in[0];
  const int*   eidx = (const int*)d_in[1];   // [2,E]: src=eidx[0..E), dst=eidx[E..2E)
  const int*   batch= (const int*)d_in[2];
  const float* W    = (const float*)d_in[3]; // [L,H,H]
  const float* wih  = (const float*)d_in[4]; // [3H,H]
  const float* whh  = (const float*)d_in[5];
  const float* bih  = (const float*)d_in[6];
  const float* bhh  = (const float*)d_in[7];
  const float* gw1  = (const float*)d_in[8]; // [H,GH]
  const float* gb1  = (const float*)d_in[9];
  const float* gw2  = (const float*)d_in[10];// [GH,1]
  const float* gb2  = (const float*)d_in[11];

  float* out      = (float*)d_out;           // [NG*H]
  float* gate_out = out + NG*H;              // [NN]

  float* ws    = (float*)d_ws;
  float* h     = ws;                          // NN*H
  float* aggH  = h + (size_t)NN*H;            // NN*H
  float* gbuf  = aggH + (size_t)NN*H;         // NN
  float* whhT  = gbuf + NN;                   // 450*H
  float* Wc    = whhT + 450*H;                // NL*H*450
  int*   cnt   = (int*)(Wc + (size_t)NL*H*450); // NN
  int*   rowptr= cnt + NN;                    // NN+1
  int*   cursor= rowptr + NN + 1;             // NN
  int*   csr   = cursor + NN;                 // NE

  const int* esrc = eidx;
  const int* edst = eidx + NE;

  // CSR build (once per launch, reused for all 5 layers)
  hipMemsetAsync(cnt, 0, sizeof(int)*NN, stream);
  k_hist<<<(NE+255)/256, 256, 0, stream>>>(edst, cnt);
  k_scan<<<1, 1024, 0, stream>>>(cnt, rowptr, cursor);
  k_fill<<<(NE+255)/256, 256, 0, stream>>>(esrc, edst, cursor, csr);

  // weight prep
  k_transpose<<<(450*H + 255)/256, 256, 0, stream>>>(whh, whhT);
  k_wc<<<(NL*H*450 + 255)/256, 256, 0, stream>>>(W, wih, Wc);

  hipMemcpyAsync(h, x, sizeof(float)*(size_t)NN*H, hipMemcpyDeviceToDevice, stream);

  for (int l = 0; l < NL; ++l){
    k_gather<<<NN/4, 256, 0, stream>>>(h, rowptr, csr, aggH);
    k_gru<<<NN/32, 256, 0, stream>>>(aggH, h, Wc + (size_t)l*H*450, whhT, bih, bhh);
  }
  k_gatepre<<<NN/32, 256, 0, stream>>>(h, gw1, gb1, gw2, gb2, gbuf);
  k_readout<<<NG, 256, 0, stream>>>(gbuf, h, batch, out, gate_out);
}

// Round 3
// 1761.407 us; speedup vs baseline: 5.1264x; 2.7038x over previous
//
#include <hip/hip_runtime.h>
#include <math.h>

#define NN 100000
#define NE 1600000
#define H 150
#define NG 256
#define NL 5
#define GH 200
#define HS 160          // padded bf16 row stride (elements)
#define LS 168          // LDS row stride in bf16 elems (2-way-conflict-free)
#define CHN 1563        // ceil(NN/64)

typedef unsigned short u16;
typedef unsigned int   u32;
typedef __attribute__((ext_vector_type(8))) short bf16x8;
typedef __attribute__((ext_vector_type(4))) float f32x4;

__device__ __forceinline__ float sigf(float x){ return 1.0f/(1.0f+expf(-x)); }
__device__ __forceinline__ float bf2f(u32 lo16){ u32 t = lo16 << 16; return __builtin_bit_cast(float, t); }
__device__ __forceinline__ u16 f2bf(float f){
  u32 u = __builtin_bit_cast(u32, f);
  u += 0x7fffu + ((u >> 16) & 1u);
  return (u16)(u >> 16);
}

// ---- CSR build ----
__global__ void k_hist(const int* __restrict__ ed, int* __restrict__ cnt){
  int e = blockIdx.x*256 + threadIdx.x;
  if (e < NE) atomicAdd(&cnt[ed[e]], 1);
}

__global__ __launch_bounds__(1024) void k_scan(const int* __restrict__ cnt,
        int* __restrict__ rowptr, int* __restrict__ cursor){
  __shared__ int tmp[1024];
  __shared__ int carry_s;
  const int tid = threadIdx.x;
  if (tid == 0){ carry_s = 0; rowptr[0] = 0; }
  __syncthreads();
  for (int base = 0; base < NN; base += 1024){
    int i = base + tid;
    int v = (i < NN) ? cnt[i] : 0;
    tmp[tid] = v;
    __syncthreads();
    for (int off = 1; off < 1024; off <<= 1){
      int t = (tid >= off) ? tmp[tid - off] : 0;
      __syncthreads();
      tmp[tid] += t;
      __syncthreads();
    }
    int carry = carry_s;
    if (i < NN){
      int incl = carry + tmp[tid];
      rowptr[i+1] = incl;
      cursor[i]   = incl - v;
    }
    __syncthreads();
    if (tid == 1023) carry_s = carry + tmp[1023];
    __syncthreads();
  }
}

__global__ void k_fill(const int* __restrict__ es, const int* __restrict__ ed,
                       int* __restrict__ cursor, int* __restrict__ csr){
  int e = blockIdx.x*256 + threadIdx.x;
  if (e < NE){
    int pos = atomicAdd(&cursor[ed[e]], 1);
    csr[pos] = es[e];
  }
}

// ---- weight prep ----
// Wc[l][k*450 + j] = sum_t W[l][k][t] * wih[j][t]
__global__ __launch_bounds__(256) void k_wc(const float* __restrict__ W,
        const float* __restrict__ wih, float* __restrict__ Wc){
  int idx = blockIdx.x*256 + threadIdx.x;
  if (idx >= NL*H*450) return;
  int l = idx / (H*450);
  int rem = idx - l*H*450;
  int k = rem / 450;
  int j = rem - k*450;
  const float* Wr = W   + (size_t)l*H*H + (size_t)k*H;
  const float* wr = wih + (size_t)j*H;
  float acc = 0.f;
  for (int t = 0; t < H; ++t) acc = fmaf(Wr[t], wr[t], acc);
  Wc[idx] = acc;
}

// pack Wc -> wbi: [l][ct(10)][ks(5)][mat(3)][lane(64)][8] bf16, B[k][col] frag order
__global__ void k_packi(const float* __restrict__ Wc, short* __restrict__ wbi){
  int idx = blockIdx.x*256 + threadIdx.x;    // total NL*10*5*3*512 = 384000
  int li = idx & 511;
  int q = idx >> 9;
  int mat = q % 3; q /= 3;
  int ks = q % 5;  q /= 5;
  int ct = q % 10; int l = q / 10;
  int lane = li >> 3, j = li & 7;
  int k = ks*32 + ((lane >> 4) << 3) + j;
  int col = ct*16 + (lane & 15);
  float v = (k < H && col < H) ? Wc[(size_t)l*H*450 + (size_t)k*450 + mat*H + col] : 0.f;
  wbi[idx] = (short)f2bf(v);
}

// pack whh -> wbh: [ct][ks][mat][512]; B[k][col] = whh[(mat*150+col)*150 + k]
__global__ void k_packh(const float* __restrict__ whh, short* __restrict__ wbh){
  int idx = blockIdx.x*256 + threadIdx.x;    // total 10*5*3*512 = 76800
  int li = idx & 511;
  int q = idx >> 9;
  int mat = q % 3; q /= 3;
  int ks = q % 5;  int ct = q / 5;
  int lane = li >> 3, j = li & 7;
  int k = ks*32 + ((lane >> 4) << 3) + j;
  int col = ct*16 + (lane & 15);
  float v = (k < H && col < H) ? whh[(size_t)(mat*H + col)*H + k] : 0.f;
  wbh[idx] = (short)f2bf(v);
}

// pack gw1 -> gw1b: [ct(13)][ks(5)][512]; B[k][col] = gw1[k*200+col]
__global__ void k_packg(const float* __restrict__ gw1, short* __restrict__ gw1b){
  int idx = blockIdx.x*256 + threadIdx.x;    // total 13*5*512 = 33280
  int li = idx & 511;
  int q = idx >> 9;
  int ks = q % 5;  int ct = q / 5;
  int lane = li >> 3, j = li & 7;
  int k = ks*32 + ((lane >> 4) << 3) + j;
  int col = ct*16 + (lane & 15);
  float v = (k < H && col < GH) ? gw1[(size_t)k*GH + col] : 0.f;
  gw1b[idx] = (short)f2bf(v);
}

// x (fp32) -> hb (bf16, stride 160, zero pad)
__global__ void k_cvt(const float* __restrict__ x, short* __restrict__ hb){
  int idx = blockIdx.x*256 + threadIdx.x;    // NN*80
  if (idx >= NN*80) return;
  int n = idx / 80, c2 = idx - n*80;
  int c = c2*2;
  float lo = (c   < H) ? x[(size_t)n*H + c]   : 0.f;
  float hi = (c+1 < H) ? x[(size_t)n*H + c+1] : 0.f;
  ((u32*)hb)[idx] = (u32)f2bf(lo) | ((u32)f2bf(hi) << 16);
}

// aggb[n] = sum_{e: dst==n} hb[src[e]]  (bf16 in, fp32 accum, bf16 out)
__global__ __launch_bounds__(256) void k_gather(const short* __restrict__ hb,
        const int* __restrict__ rowptr, const int* __restrict__ csr,
        short* __restrict__ aggb){
  const int lane = threadIdx.x & 63;
  const int n = blockIdx.x*4 + (threadIdx.x >> 6);
  if (n >= NN) return;
  const int s0 = rowptr[n], s1 = rowptr[n+1];
  const u32* h32 = (const u32*)hb;
  const bool ext = lane < 16;
  float x0=0.f, x1=0.f, y0=0.f, y1=0.f;
  int j = s0;
  for (; j + 1 < s1; j += 2){
    const u32* r0 = h32 + (size_t)csr[j]*80;
    const u32* r1 = h32 + (size_t)csr[j+1]*80;
    u32 v0 = r0[lane], v1 = r1[lane];
    x0 += bf2f(v0 & 0xffffu) + bf2f(v1 & 0xffffu);
    x1 += bf2f(v0 >> 16)     + bf2f(v1 >> 16);
    if (ext){
      u32 u0 = r0[64+lane], u1 = r1[64+lane];
      y0 += bf2f(u0 & 0xffffu) + bf2f(u1 & 0xffffu);
      y1 += bf2f(u0 >> 16)     + bf2f(u1 >> 16);
    }
  }
  if (j < s1){
    const u32* r0 = h32 + (size_t)csr[j]*80;
    u32 v0 = r0[lane];
    x0 += bf2f(v0 & 0xffffu); x1 += bf2f(v0 >> 16);
    if (ext){
      u32 u0 = r0[64+lane];
      y0 += bf2f(u0 & 0xffffu); y1 += bf2f(u0 >> 16);
    }
  }
  u32* o = (u32*)aggb + (size_t)n*80;
  o[lane] = (u32)f2bf(x0) | ((u32)f2bf(x1) << 16);
  if (ext) o[64+lane] = (u32)f2bf(y0) | ((u32)f2bf(y1) << 16);
}

// ---- fused GRU via MFMA ----
// gi = aggb @ [Wc gates], gh = hb @ [whh^T gates]; h = GRU update (fp32 master), hb = bf16(h)
__global__ __launch_bounds__(512, 2) void k_gru(
    const short* __restrict__ aggb, short* __restrict__ hb, float* __restrict__ h,
    const short* __restrict__ wbi_l, const short* __restrict__ wbh,
    const float* __restrict__ bih, const float* __restrict__ bhh){
  __shared__ short sa[64*LS];
  __shared__ short sh[64*LS];
  const int tid = threadIdx.x;
  const int w = tid >> 6, lane = tid & 63;
  const int l16 = lane & 15, g = lane >> 4, g8 = g*8;

  // zero LDS pad cols 160..167 (once)
  for (int i = tid; i < 64*4; i += 512){
    int r = i >> 2, c = i & 3;
    *(u32*)&sa[r*LS + 160 + c*2] = 0u;
    *(u32*)&sh[r*LS + 160 + c*2] = 0u;
  }

  for (int chunk = blockIdx.x; chunk < CHN; chunk += gridDim.x){
    __syncthreads();
    const int row0 = chunk*64;
    for (int i = tid; i < 64*20; i += 512){
      int r = i/20, c = i - r*20;
      int gr = row0 + r;
      bf16x8 va = {0,0,0,0,0,0,0,0}, vh = {0,0,0,0,0,0,0,0};
      if (gr < NN){
        va = *(const bf16x8*)&aggb[(size_t)gr*HS + c*8];
        vh = *(const bf16x8*)&hb  [(size_t)gr*HS + c*8];
      }
      *(bf16x8*)&sa[r*LS + c*8] = va;
      *(bf16x8*)&sh[r*LS + c*8] = vh;
    }
    __syncthreads();

    int curct = -1;
    bf16x8 B0[5],B1[5],B2[5],B3[5],B4[5],B5[5];
    float bir=0,biz=0,bin_=0,bhr=0,bhz=0,bhn=0;
    int col = 0; bool cv = false;
    for (int t = w*5; t < w*5 + 5; ++t){
      const int ct = t >> 2, rt = t & 3;
      if (ct != curct){
        curct = ct;
        const short* pi = wbi_l + (size_t)ct*(5*3*512) + lane*8;
        const short* ph = wbh   + (size_t)ct*(5*3*512) + lane*8;
        #pragma unroll
        for (int ks = 0; ks < 5; ++ks){
          B0[ks] = *(const bf16x8*)&pi[(ks*3+0)*512];
          B1[ks] = *(const bf16x8*)&pi[(ks*3+1)*512];
          B2[ks] = *(const bf16x8*)&pi[(ks*3+2)*512];
          B3[ks] = *(const bf16x8*)&ph[(ks*3+0)*512];
          B4[ks] = *(const bf16x8*)&ph[(ks*3+1)*512];
          B5[ks] = *(const bf16x8*)&ph[(ks*3+2)*512];
        }
        col = ct*16 + l16;
        cv = col < H;
        bir = cv ? bih[col] : 0.f;  biz = cv ? bih[H+col] : 0.f;  bin_ = cv ? bih[2*H+col] : 0.f;
        bhr = cv ? bhh[col] : 0.f;  bhz = cv ? bhh[H+col] : 0.f;  bhn  = cv ? bhh[2*H+col] : 0.f;
      }
      f32x4 a0={0,0,0,0},a1={0,0,0,0},a2={0,0,0,0},a3={0,0,0,0},a4={0,0,0,0},a5={0,0,0,0};
      const int lr = rt*16 + l16;
      #pragma unroll
      for (int ks = 0; ks < 5; ++ks){
        bf16x8 aA = *(const bf16x8*)&sa[lr*LS + ks*32 + g8];
        bf16x8 aH = *(const bf16x8*)&sh[lr*LS + ks*32 + g8];
        a0 = __builtin_amdgcn_mfma_f32_16x16x32_bf16(aA, B0[ks], a0, 0,0,0);
        a1 = __builtin_amdgcn_mfma_f32_16x16x32_bf16(aA, B1[ks], a1, 0,0,0);
        a2 = __builtin_amdgcn_mfma_f32_16x16x32_bf16(aA, B2[ks], a2, 0,0,0);
        a3 = __builtin_amdgcn_mfma_f32_16x16x32_bf16(aH, B3[ks], a3, 0,0,0);
        a4 = __builtin_amdgcn_mfma_f32_16x16x32_bf16(aH, B4[ks], a4, 0,0,0);
        a5 = __builtin_amdgcn_mfma_f32_16x16x32_bf16(aH, B5[ks], a5, 0,0,0);
      }
      if (cv){
        #pragma unroll
        for (int r = 0; r < 4; ++r){
          int grow = row0 + rt*16 + g*4 + r;
          if (grow < NN){
            float rr = sigf(a0[r]+bir + a3[r]+bhr);
            float zz = sigf(a1[r]+biz + a4[r]+bhz);
            float nn = tanhf(a2[r]+bin_ + rr*(a5[r]+bhn));
            size_t hidx = (size_t)grow*H + col;
            float hold = h[hidx];
            float hnew = (1.f-zz)*nn + zz*hold;
            h[hidx] = hnew;
            hb[(size_t)grow*HS + col] = (short)f2bf(hnew);
          }
        }
      }
    }
  }
}

// gate_pre via MFMA: gbuf[n] = tanh(hb[n]@gw1+gb1)@gw2 + gb2
__global__ __launch_bounds__(256) void k_gatepre(const short* __restrict__ hb,
      const short* __restrict__ gw1b, const float* __restrict__ gb1,
      const float* __restrict__ gw2, const float* __restrict__ gb2,
      float* __restrict__ gbuf){
  __shared__ short sh[64*LS];
  __shared__ float part[4][4][4][4];   // [wave][rt][g][r]
  const int tid = threadIdx.x;
  const int w = tid >> 6, lane = tid & 63;
  const int l16 = lane & 15, g = lane >> 4, g8 = g*8;
  const int chunk = blockIdx.x, row0 = chunk*64;

  for (int i = tid; i < 64*4; i += 256){
    int r = i >> 2, c = i & 3;
    *(u32*)&sh[r*LS + 160 + c*2] = 0u;
  }
  for (int i = tid; i < 64*20; i += 256){
    int r = i/20, c = i - r*20;
    int gr = row0 + r;
    bf16x8 v = {0,0,0,0,0,0,0,0};
    if (gr < NN) v = *(const bf16x8*)&hb[(size_t)gr*HS + c*8];
    *(bf16x8*)&sh[r*LS + c*8] = v;
  }
  __syncthreads();

  float acc[4][4];
  #pragma unroll
  for (int rt=0; rt<4; ++rt){
    #pragma unroll
    for (int r=0; r<4; ++r) acc[rt][r] = 0.f;
  }
  for (int ct = w; ct < 13; ct += 4){
    bf16x8 B[5];
    const short* p = gw1b + (size_t)(ct*5)*512 + lane*8;
    #pragma unroll
    for (int ks = 0; ks < 5; ++ks) B[ks] = *(const bf16x8*)&p[ks*512];
    int col = ct*16 + l16;
    bool cv = col < GH;
    float g2 = cv ? gw2[col] : 0.f;
    float b1 = cv ? gb1[col] : 0.f;
    #pragma unroll
    for (int rt = 0; rt < 4; ++rt){
      f32x4 d = {0,0,0,0};
      #pragma unroll
      for (int ks = 0; ks < 5; ++ks){
        bf16x8 aH = *(const bf16x8*)&sh[(rt*16 + l16)*LS + ks*32 + g8];
        d = __builtin_amdgcn_mfma_f32_16x16x32_bf16(aH, B[ks], d, 0,0,0);
      }
      if (cv){
        #pragma unroll
        for (int r = 0; r < 4; ++r) acc[rt][r] += tanhf(d[r] + b1) * g2;
      }
    }
  }
  #pragma unroll
  for (int rt = 0; rt < 4; ++rt){
    #pragma unroll
    for (int r = 0; r < 4; ++r){
      float v = acc[rt][r];
      v += __shfl_xor(v, 1); v += __shfl_xor(v, 2);
      v += __shfl_xor(v, 4); v += __shfl_xor(v, 8);
      if (l16 == 0) part[w][rt][g][r] = v;
    }
  }
  __syncthreads();
  if (tid < 64){
    int rt = tid >> 4, gg = (tid >> 2) & 3, r = tid & 3;
    int grow = row0 + tid;
    if (grow < NN)
      gbuf[grow] = part[0][rt][gg][r] + part[1][rt][gg][r]
                 + part[2][rt][gg][r] + part[3][rt][gg][r] + gb2[0];
  }
}

// per-graph segment softmax + weighted sum (batch sorted); h fp32
__global__ __launch_bounds__(256) void k_readout(float* __restrict__ gatebuf,
    const float* __restrict__ h, const int* __restrict__ batch,
    float* __restrict__ out, float* __restrict__ gate_out){
  const int g = blockIdx.x;
  const int tid = threadIdx.x;
  int lo=0, hi=NN;
  while (lo<hi){ int mid=(lo+hi)>>1; if (batch[mid] < g) lo=mid+1; else hi=mid; }
  const int start = lo;
  hi = NN;
  while (lo<hi){ int mid=(lo+hi)>>1; if (batch[mid] < g+1) lo=mid+1; else hi=mid; }
  const int end = lo;

  __shared__ float red[256];
  __shared__ float s_max, s_inv;
  float mx = -INFINITY;
  for (int n = start+tid; n < end; n += 256) mx = fmaxf(mx, gatebuf[n]);
  red[tid]=mx; __syncthreads();
  for (int s=128; s>=1; s>>=1){ if (tid<s) red[tid]=fmaxf(red[tid],red[tid+s]); __syncthreads(); }
  if (tid==0) s_max = red[0];
  __syncthreads();
  const float gmax = s_max;
  float sum = 0.f;
  for (int n = start+tid; n < end; n += 256){
    float e = expf(gatebuf[n]-gmax);
    gatebuf[n] = e;
    sum += e;
  }
  red[tid]=sum; __syncthreads();
  for (int s=128; s>=1; s>>=1){ if (tid<s) red[tid]+=red[tid+s]; __syncthreads(); }
  if (tid==0) s_inv = 1.0f/(red[0] + 1e-16f);
  __syncthreads();
  const float inv = s_inv;
  for (int n = start+tid; n < end; n += 256) gate_out[n] = gatebuf[n]*inv;
  if (tid < H){
    float acc = 0.f;
    for (int n = start; n < end; ++n)
      acc = fmaf(gatebuf[n], h[(size_t)n*H + tid], acc);
    out[g*H + tid] = acc*inv;
  }
}

extern "C" void kernel_launch(void* const* d_in, const int* in_sizes, int n_in,
                              void* d_out, int out_size, void* d_ws, size_t ws_size,
                              hipStream_t stream) {
  (void)in_sizes; (void)n_in; (void)out_size; (void)ws_size;
  const float* x    = (const float*)d_in[0];
  const int*   eidx = (const int*)d_in[1];
  const int*   batch= (const int*)d_in[2];
  const float* W    = (const float*)d_in[3];
  const float* wih  = (const float*)d_in[4];
  const float* whh  = (const float*)d_in[5];
  const float* bih  = (const float*)d_in[6];
  const float* bhh  = (const float*)d_in[7];
  const float* gw1  = (const float*)d_in[8];
  const float* gb1  = (const float*)d_in[9];
  const float* gw2  = (const float*)d_in[10];
  const float* gb2  = (const float*)d_in[11];

  float* out      = (float*)d_out;
  float* gate_out = out + NG*H;

  char* p = (char*)d_ws;
  float* h     = (float*)p;  p += (size_t)NN*H*4;        // 60 MB
  float* gbuf  = (float*)p;  p += (size_t)NN*4;          // 0.4 MB
  float* Wc    = (float*)p;  p += (size_t)NL*H*450*4;    // 1.35 MB
  short* hb    = (short*)p;  p += (size_t)NN*HS*2;       // 32 MB
  short* aggb  = (short*)p;  p += (size_t)NN*HS*2;       // 32 MB
  short* wbi   = (short*)p;  p += (size_t)NL*76800*2;
  short* wbh   = (short*)p;  p += (size_t)76800*2;
  short* gw1b  = (short*)p;  p += (size_t)33280*2;
  int*   cnt   = (int*)p;    p += (size_t)NN*4;
  int*   rowptr= (int*)p;    p += (size_t)(NN+1)*4;
  int*   cursor= (int*)p;    p += (size_t)NN*4;
  int*   csr   = (int*)p;    p += (size_t)NE*4;

  const int* esrc = eidx;
  const int* edst = eidx + NE;

  hipMemsetAsync(cnt, 0, sizeof(int)*NN, stream);
  k_hist<<<(NE+255)/256, 256, 0, stream>>>(edst, cnt);
  k_scan<<<1, 1024, 0, stream>>>(cnt, rowptr, cursor);
  k_fill<<<(NE+255)/256, 256, 0, stream>>>(esrc, edst, cursor, csr);

  k_wc   <<<(NL*H*450+255)/256, 256, 0, stream>>>(W, wih, Wc);
  k_packi<<<1500, 256, 0, stream>>>(Wc, wbi);
  k_packh<<<300,  256, 0, stream>>>(whh, wbh);
  k_packg<<<130,  256, 0, stream>>>(gw1, gw1b);

  k_cvt<<<(NN*80+255)/256, 256, 0, stream>>>(x, hb);
  hipMemcpyAsync(h, x, sizeof(float)*(size_t)NN*H, hipMemcpyDeviceToDevice, stream);

  for (int l = 0; l < NL; ++l){
    k_gather<<<NN/4, 256, 0, stream>>>(hb, rowptr, csr, aggb);
    k_gru<<<256, 512, 0, stream>>>(aggb, hb, h, wbi + (size_t)l*76800, wbh, bih, bhh);
  }
  k_gatepre<<<CHN, 256, 0, stream>>>(hb, gw1b, gb1, gw2, gb2, gbuf);
  k_readout<<<NG, 256, 0, stream>>>(gbuf, h, batch, out, gate_out);
}

// Round 4
// 1513.065 us; speedup vs baseline: 5.9678x; 1.1641x over previous
//
#include <hip/hip_runtime.h>
#include <math.h>

#define NN 100000
#define NE 1600000
#define H 150
#define NG 256
#define NL 5
#define GH 200
#define HS 160          // padded bf16 row stride (elements)
#define LS 168          // LDS row stride in bf16 elems (2-way-conflict-free)
#define CHN 1563        // ceil(NN/64)
#define SNB 98          // ceil(NN/1024)

typedef unsigned short u16;
typedef unsigned int   u32;
typedef __attribute__((ext_vector_type(8))) short bf16x8;
typedef __attribute__((ext_vector_type(4))) float f32x4;

__device__ __forceinline__ float sigf(float x){ return 1.0f/(1.0f+expf(-x)); }
__device__ __forceinline__ float bf2f(u32 lo16){ u32 t = lo16 << 16; return __builtin_bit_cast(float, t); }
__device__ __forceinline__ u16 f2bf(float f){
  u32 u = __builtin_bit_cast(u32, f);
  u += 0x7fffu + ((u >> 16) & 1u);
  return (u16)(u >> 16);
}

// ---- CSR build ----
__global__ void k_hist(const int* __restrict__ ed, int* __restrict__ cnt){
  int e = blockIdx.x*256 + threadIdx.x;
  if (e < NE) atomicAdd(&cnt[ed[e]], 1);
}

// pass 1: per-1024-chunk partial sums
__global__ __launch_bounds__(256) void k_scan1(const int* __restrict__ cnt, int* __restrict__ part){
  __shared__ int red[256];
  const int b = blockIdx.x, tid = threadIdx.x;
  const int base = b*1024;
  int s = 0;
  #pragma unroll
  for (int i = 0; i < 4; ++i){
    int idx = base + tid + i*256;
    s += (idx < NN) ? cnt[idx] : 0;
  }
  red[tid] = s; __syncthreads();
  for (int st = 128; st >= 1; st >>= 1){
    if (tid < st) red[tid] += red[tid+st];
    __syncthreads();
  }
  if (tid == 0) part[b] = red[0];
}

// pass 2: exclusive scan of SNB partials (one wave, 2 per lane)
__global__ void k_scan2(int* __restrict__ part){
  const int t = threadIdx.x;
  int v0 = (2*t   < SNB) ? part[2*t]   : 0;
  int v1 = (2*t+1 < SNB) ? part[2*t+1] : 0;
  int s = v0 + v1, x = s;
  #pragma unroll
  for (int off = 1; off < 64; off <<= 1){
    int tt = __shfl_up(x, off);
    if (t >= off) x += tt;
  }
  int excl = x - s;
  if (2*t   < SNB) part[2*t]   = excl;
  if (2*t+1 < SNB) part[2*t+1] = excl + v0;
}

// pass 3: local shfl scan + block offset -> rowptr, cursor
__global__ __launch_bounds__(1024) void k_scan3(const int* __restrict__ cnt,
        const int* __restrict__ part, int* __restrict__ rowptr, int* __restrict__ cursor){
  __shared__ int wsum[16];
  const int b = blockIdx.x, tid = threadIdx.x;
  const int wid = tid >> 6, lane = tid & 63;
  const int idx = b*1024 + tid;
  int v = (idx < NN) ? cnt[idx] : 0;
  int x = v;
  #pragma unroll
  for (int off = 1; off < 64; off <<= 1){
    int t = __shfl_up(x, off);
    if (lane >= off) x += t;
  }
  if (lane == 63) wsum[wid] = x;
  __syncthreads();
  if (tid < 16){
    int s = wsum[tid];
    int y = s;
    #pragma unroll
    for (int off = 1; off < 16; off <<= 1){
      int t = __shfl_up(y, off);
      if (tid >= off) y += t;
    }
    wsum[tid] = y - s;   // exclusive wave offset
  }
  __syncthreads();
  if (idx < NN){
    int incl = part[b] + wsum[wid] + x;
    rowptr[idx+1] = incl;
    cursor[idx]   = incl - v;
  }
  if (idx == 0) rowptr[0] = 0;
}

__global__ void k_fill(const int* __restrict__ es, const int* __restrict__ ed,
                       int* __restrict__ cursor, int* __restrict__ csr){
  int e = blockIdx.x*256 + threadIdx.x;
  if (e < NE){
    int pos = atomicAdd(&cursor[ed[e]], 1);
    csr[pos] = es[e];
  }
}

// ---- weight prep ----
__global__ __launch_bounds__(256) void k_wc(const float* __restrict__ W,
        const float* __restrict__ wih, float* __restrict__ Wc){
  int idx = blockIdx.x*256 + threadIdx.x;
  if (idx >= NL*H*450) return;
  int l = idx / (H*450);
  int rem = idx - l*H*450;
  int k = rem / 450;
  int j = rem - k*450;
  const float* Wr = W   + (size_t)l*H*H + (size_t)k*H;
  const float* wr = wih + (size_t)j*H;
  float acc = 0.f;
  for (int t = 0; t < H; ++t) acc = fmaf(Wr[t], wr[t], acc);
  Wc[idx] = acc;
}

__global__ void k_packi(const float* __restrict__ Wc, short* __restrict__ wbi){
  int idx = blockIdx.x*256 + threadIdx.x;    // NL*10*5*3*512
  int li = idx & 511;
  int q = idx >> 9;
  int mat = q % 3; q /= 3;
  int ks = q % 5;  q /= 5;
  int ct = q % 10; int l = q / 10;
  int lane = li >> 3, j = li & 7;
  int k = ks*32 + ((lane >> 4) << 3) + j;
  int col = ct*16 + (lane & 15);
  float v = (k < H && col < H) ? Wc[(size_t)l*H*450 + (size_t)k*450 + mat*H + col] : 0.f;
  wbi[idx] = (short)f2bf(v);
}

__global__ void k_packh(const float* __restrict__ whh, short* __restrict__ wbh){
  int idx = blockIdx.x*256 + threadIdx.x;    // 10*5*3*512
  int li = idx & 511;
  int q = idx >> 9;
  int mat = q % 3; q /= 3;
  int ks = q % 5;  int ct = q / 5;
  int lane = li >> 3, j = li & 7;
  int k = ks*32 + ((lane >> 4) << 3) + j;
  int col = ct*16 + (lane & 15);
  float v = (k < H && col < H) ? whh[(size_t)(mat*H + col)*H + k] : 0.f;
  wbh[idx] = (short)f2bf(v);
}

__global__ void k_packg(const float* __restrict__ gw1, short* __restrict__ gw1b){
  int idx = blockIdx.x*256 + threadIdx.x;    // 13*5*512
  int li = idx & 511;
  int q = idx >> 9;
  int ks = q % 5;  int ct = q / 5;
  int lane = li >> 3, j = li & 7;
  int k = ks*32 + ((lane >> 4) << 3) + j;
  int col = ct*16 + (lane & 15);
  float v = (k < H && col < GH) ? gw1[(size_t)k*GH + col] : 0.f;
  gw1b[idx] = (short)f2bf(v);
}

__global__ void k_cvt(const float* __restrict__ x, short* __restrict__ hb){
  int idx = blockIdx.x*256 + threadIdx.x;    // NN*80
  if (idx >= NN*80) return;
  int n = idx / 80, c2 = idx - n*80;
  int c = c2*2;
  float lo = (c   < H) ? x[(size_t)n*H + c]   : 0.f;
  float hi = (c+1 < H) ? x[(size_t)n*H + c+1] : 0.f;
  ((u32*)hb)[idx] = (u32)f2bf(lo) | ((u32)f2bf(hi) << 16);
}

// aggb[n] = sum_{e: dst==n} hb[src[e]]  (bf16 in, fp32 accum, bf16 out)
__global__ __launch_bounds__(256) void k_gather(const short* __restrict__ hb,
        const int* __restrict__ rowptr, const int* __restrict__ csr,
        short* __restrict__ aggb){
  const int lane = threadIdx.x & 63;
  const int n = blockIdx.x*4 + (threadIdx.x >> 6);
  if (n >= NN) return;
  const int s0 = rowptr[n], s1 = rowptr[n+1];
  const u32* h32 = (const u32*)hb;
  const bool ext = lane < 16;
  float x0=0.f, x1=0.f, y0=0.f, y1=0.f;
  int j = s0;
  for (; j + 3 < s1; j += 4){
    const u32* r0 = h32 + (size_t)csr[j]*80;
    const u32* r1 = h32 + (size_t)csr[j+1]*80;
    const u32* r2 = h32 + (size_t)csr[j+2]*80;
    const u32* r3 = h32 + (size_t)csr[j+3]*80;
    u32 v0 = r0[lane], v1 = r1[lane], v2 = r2[lane], v3 = r3[lane];
    u32 u0=0,u1=0,u2=0,u3=0;
    if (ext){ u0 = r0[64+lane]; u1 = r1[64+lane]; u2 = r2[64+lane]; u3 = r3[64+lane]; }
    x0 += bf2f(v0 & 0xffffu) + bf2f(v1 & 0xffffu) + bf2f(v2 & 0xffffu) + bf2f(v3 & 0xffffu);
    x1 += bf2f(v0 >> 16)     + bf2f(v1 >> 16)     + bf2f(v2 >> 16)     + bf2f(v3 >> 16);
    if (ext){
      y0 += bf2f(u0 & 0xffffu) + bf2f(u1 & 0xffffu) + bf2f(u2 & 0xffffu) + bf2f(u3 & 0xffffu);
      y1 += bf2f(u0 >> 16)     + bf2f(u1 >> 16)     + bf2f(u2 >> 16)     + bf2f(u3 >> 16);
    }
  }
  for (; j < s1; ++j){
    const u32* r0 = h32 + (size_t)csr[j]*80;
    u32 v0 = r0[lane];
    x0 += bf2f(v0 & 0xffffu); x1 += bf2f(v0 >> 16);
    if (ext){
      u32 u0 = r0[64+lane];
      y0 += bf2f(u0 & 0xffffu); y1 += bf2f(u0 >> 16);
    }
  }
  u32* o = (u32*)aggb + (size_t)n*80;
  o[lane] = (u32)f2bf(x0) | ((u32)f2bf(x1) << 16);
  if (ext) o[64+lane] = (u32)f2bf(y0) | ((u32)f2bf(y1) << 16);
}

// ---- fused GRU via MFMA ----
__global__ __launch_bounds__(512, 2) void k_gru(
    const short* __restrict__ aggb, short* __restrict__ hb, float* __restrict__ h,
    const short* __restrict__ wbi_l, const short* __restrict__ wbh,
    const float* __restrict__ bih, const float* __restrict__ bhh){
  __shared__ short sa[64*LS];
  __shared__ short sh[64*LS];
  const int tid = threadIdx.x;
  const int w = tid >> 6, lane = tid & 63;
  const int l16 = lane & 15, g = lane >> 4, g8 = g*8;

  for (int i = tid; i < 64*4; i += 512){
    int r = i >> 2, c = i & 3;
    *(u32*)&sa[r*LS + 160 + c*2] = 0u;
    *(u32*)&sh[r*LS + 160 + c*2] = 0u;
  }

  for (int chunk = blockIdx.x; chunk < CHN; chunk += gridDim.x){
    __syncthreads();
    const int row0 = chunk*64;
    for (int i = tid; i < 64*20; i += 512){
      int r = i/20, c = i - r*20;
      int gr = row0 + r;
      bf16x8 va = {0,0,0,0,0,0,0,0}, vh = {0,0,0,0,0,0,0,0};
      if (gr < NN){
        va = *(const bf16x8*)&aggb[(size_t)gr*HS + c*8];
        vh = *(const bf16x8*)&hb  [(size_t)gr*HS + c*8];
      }
      *(bf16x8*)&sa[r*LS + c*8] = va;
      *(bf16x8*)&sh[r*LS + c*8] = vh;
    }
    __syncthreads();

    int curct = -1;
    bf16x8 B0[5],B1[5],B2[5],B3[5],B4[5],B5[5];
    float bir=0,biz=0,bin_=0,bhr=0,bhz=0,bhn=0;
    int col = 0; bool cv = false;
    for (int t = w*5; t < w*5 + 5; ++t){
      const int ct = t >> 2, rt = t & 3;
      if (ct != curct){
        curct = ct;
        const short* pi = wbi_l + (size_t)ct*(5*3*512) + lane*8;
        const short* ph = wbh   + (size_t)ct*(5*3*512) + lane*8;
        #pragma unroll
        for (int ks = 0; ks < 5; ++ks){
          B0[ks] = *(const bf16x8*)&pi[(ks*3+0)*512];
          B1[ks] = *(const bf16x8*)&pi[(ks*3+1)*512];
          B2[ks] = *(const bf16x8*)&pi[(ks*3+2)*512];
          B3[ks] = *(const bf16x8*)&ph[(ks*3+0)*512];
          B4[ks] = *(const bf16x8*)&ph[(ks*3+1)*512];
          B5[ks] = *(const bf16x8*)&ph[(ks*3+2)*512];
        }
        col = ct*16 + l16;
        cv = col < H;
        bir = cv ? bih[col] : 0.f;  biz = cv ? bih[H+col] : 0.f;  bin_ = cv ? bih[2*H+col] : 0.f;
        bhr = cv ? bhh[col] : 0.f;  bhz = cv ? bhh[H+col] : 0.f;  bhn  = cv ? bhh[2*H+col] : 0.f;
      }
      f32x4 a0={0,0,0,0},a1={0,0,0,0},a2={0,0,0,0},a3={0,0,0,0},a4={0,0,0,0},a5={0,0,0,0};
      const int lr = rt*16 + l16;
      #pragma unroll
      for (int ks = 0; ks < 5; ++ks){
        bf16x8 aA = *(const bf16x8*)&sa[lr*LS + ks*32 + g8];
        bf16x8 aH = *(const bf16x8*)&sh[lr*LS + ks*32 + g8];
        a0 = __builtin_amdgcn_mfma_f32_16x16x32_bf16(aA, B0[ks], a0, 0,0,0);
        a1 = __builtin_amdgcn_mfma_f32_16x16x32_bf16(aA, B1[ks], a1, 0,0,0);
        a2 = __builtin_amdgcn_mfma_f32_16x16x32_bf16(aA, B2[ks], a2, 0,0,0);
        a3 = __builtin_amdgcn_mfma_f32_16x16x32_bf16(aH, B3[ks], a3, 0,0,0);
        a4 = __builtin_amdgcn_mfma_f32_16x16x32_bf16(aH, B4[ks], a4, 0,0,0);
        a5 = __builtin_amdgcn_mfma_f32_16x16x32_bf16(aH, B5[ks], a5, 0,0,0);
      }
      if (cv){
        #pragma unroll
        for (int r = 0; r < 4; ++r){
          int grow = row0 + rt*16 + g*4 + r;
          if (grow < NN){
            float rr = sigf(a0[r]+bir + a3[r]+bhr);
            float zz = sigf(a1[r]+biz + a4[r]+bhz);
            float nn = tanhf(a2[r]+bin_ + rr*(a5[r]+bhn));
            size_t hidx = (size_t)grow*H + col;
            float hold = h[hidx];
            float hnew = (1.f-zz)*nn + zz*hold;
            h[hidx] = hnew;
            hb[(size_t)grow*HS + col] = (short)f2bf(hnew);
          }
        }
      }
    }
  }
}

// gate_pre via MFMA
__global__ __launch_bounds__(256) void k_gatepre(const short* __restrict__ hb,
      const short* __restrict__ gw1b, const float* __restrict__ gb1,
      const float* __restrict__ gw2, const float* __restrict__ gb2,
      float* __restrict__ gbuf){
  __shared__ short sh[64*LS];
  __shared__ float part[4][4][4][4];
  const int tid = threadIdx.x;
  const int w = tid >> 6, lane = tid & 63;
  const int l16 = lane & 15, g = lane >> 4, g8 = g*8;
  const int chunk = blockIdx.x, row0 = chunk*64;

  for (int i = tid; i < 64*4; i += 256){
    int r = i >> 2, c = i & 3;
    *(u32*)&sh[r*LS + 160 + c*2] = 0u;
  }
  for (int i = tid; i < 64*20; i += 256){
    int r = i/20, c = i - r*20;
    int gr = row0 + r;
    bf16x8 v = {0,0,0,0,0,0,0,0};
    if (gr < NN) v = *(const bf16x8*)&hb[(size_t)gr*HS + c*8];
    *(bf16x8*)&sh[r*LS + c*8] = v;
  }
  __syncthreads();

  float acc[4][4];
  #pragma unroll
  for (int rt=0; rt<4; ++rt){
    #pragma unroll
    for (int r=0; r<4; ++r) acc[rt][r] = 0.f;
  }
  for (int ct = w; ct < 13; ct += 4){
    bf16x8 B[5];
    const short* p = gw1b + (size_t)(ct*5)*512 + lane*8;
    #pragma unroll
    for (int ks = 0; ks < 5; ++ks) B[ks] = *(const bf16x8*)&p[ks*512];
    int col = ct*16 + l16;
    bool cv = col < GH;
    float g2 = cv ? gw2[col] : 0.f;
    float b1 = cv ? gb1[col] : 0.f;
    #pragma unroll
    for (int rt = 0; rt < 4; ++rt){
      f32x4 d = {0,0,0,0};
      #pragma unroll
      for (int ks = 0; ks < 5; ++ks){
        bf16x8 aH = *(const bf16x8*)&sh[(rt*16 + l16)*LS + ks*32 + g8];
        d = __builtin_amdgcn_mfma_f32_16x16x32_bf16(aH, B[ks], d, 0,0,0);
      }
      if (cv){
        #pragma unroll
        for (int r = 0; r < 4; ++r) acc[rt][r] += tanhf(d[r] + b1) * g2;
      }
    }
  }
  #pragma unroll
  for (int rt = 0; rt < 4; ++rt){
    #pragma unroll
    for (int r = 0; r < 4; ++r){
      float v = acc[rt][r];
      v += __shfl_xor(v, 1); v += __shfl_xor(v, 2);
      v += __shfl_xor(v, 4); v += __shfl_xor(v, 8);
      if (l16 == 0) part[w][rt][g][r] = v;
    }
  }
  __syncthreads();
  if (tid < 64){
    int rt = tid >> 4, gg = (tid >> 2) & 3, r = tid & 3;
    int grow = row0 + tid;
    if (grow < NN)
      gbuf[grow] = part[0][rt][gg][r] + part[1][rt][gg][r]
                 + part[2][rt][gg][r] + part[3][rt][gg][r] + gb2[0];
  }
}

// per-graph segment softmax + weighted sum
__global__ __launch_bounds__(256) void k_readout(float* __restrict__ gatebuf,
    const float* __restrict__ h, const int* __restrict__ batch,
    float* __restrict__ out, float* __restrict__ gate_out){
  const int g = blockIdx.x;
  const int tid = threadIdx.x;
  int lo=0, hi=NN;
  while (lo<hi){ int mid=(lo+hi)>>1; if (batch[mid] < g) lo=mid+1; else hi=mid; }
  const int start = lo;
  hi = NN;
  while (lo<hi){ int mid=(lo+hi)>>1; if (batch[mid] < g+1) lo=mid+1; else hi=mid; }
  const int end = lo;

  __shared__ float red[256];
  __shared__ float s_max, s_inv;
  float mx = -INFINITY;
  for (int n = start+tid; n < end; n += 256) mx = fmaxf(mx, gatebuf[n]);
  red[tid]=mx; __syncthreads();
  for (int s=128; s>=1; s>>=1){ if (tid<s) red[tid]=fmaxf(red[tid],red[tid+s]); __syncthreads(); }
  if (tid==0) s_max = red[0];
  __syncthreads();
  const float gmax = s_max;
  float sum = 0.f;
  for (int n = start+tid; n < end; n += 256){
    float e = expf(gatebuf[n]-gmax);
    gatebuf[n] = e;
    sum += e;
  }
  red[tid]=sum; __syncthreads();
  for (int s=128; s>=1; s>>=1){ if (tid<s) red[tid]+=red[tid+s]; __syncthreads(); }
  if (tid==0) s_inv = 1.0f/(red[0] + 1e-16f);
  __syncthreads();
  const float inv = s_inv;
  for (int n = start+tid; n < end; n += 256) gate_out[n] = gatebuf[n]*inv;
  if (tid < H){
    float acc = 0.f;
    for (int n = start; n < end; ++n)
      acc = fmaf(gatebuf[n], h[(size_t)n*H + tid], acc);
    out[g*H + tid] = acc*inv;
  }
}

extern "C" void kernel_launch(void* const* d_in, const int* in_sizes, int n_in,
                              void* d_out, int out_size, void* d_ws, size_t ws_size,
                              hipStream_t stream) {
  (void)in_sizes; (void)n_in; (void)out_size; (void)ws_size;
  const float* x    = (const float*)d_in[0];
  const int*   eidx = (const int*)d_in[1];
  const int*   batch= (const int*)d_in[2];
  const float* W    = (const float*)d_in[3];
  const float* wih  = (const float*)d_in[4];
  const float* whh  = (const float*)d_in[5];
  const float* bih  = (const float*)d_in[6];
  const float* bhh  = (const float*)d_in[7];
  const float* gw1  = (const float*)d_in[8];
  const float* gb1  = (const float*)d_in[9];
  const float* gw2  = (const float*)d_in[10];
  const float* gb2  = (const float*)d_in[11];

  float* out      = (float*)d_out;
  float* gate_out = out + NG*H;

  char* p = (char*)d_ws;
  float* h     = (float*)p;  p += (size_t)NN*H*4;
  float* gbuf  = (float*)p;  p += (size_t)NN*4;
  float* Wc    = (float*)p;  p += (size_t)NL*H*450*4;
  short* hb    = (short*)p;  p += (size_t)NN*HS*2;
  short* aggb  = (short*)p;  p += (size_t)NN*HS*2;
  short* wbi   = (short*)p;  p += (size_t)NL*76800*2;
  short* wbh   = (short*)p;  p += (size_t)76800*2;
  short* gw1b  = (short*)p;  p += (size_t)33280*2;
  int*   cnt   = (int*)p;    p += (size_t)NN*4;
  int*   rowptr= (int*)p;    p += (size_t)(NN+1)*4;
  int*   cursor= (int*)p;    p += (size_t)NN*4;
  int*   csr   = (int*)p;    p += (size_t)NE*4;
  int*   spart = (int*)p;    p += (size_t)SNB*4;

  const int* esrc = eidx;
  const int* edst = eidx + NE;

  hipMemsetAsync(cnt, 0, sizeof(int)*NN, stream);
  k_hist<<<(NE+255)/256, 256, 0, stream>>>(edst, cnt);
  k_scan1<<<SNB, 256, 0, stream>>>(cnt, spart);
  k_scan2<<<1, 64, 0, stream>>>(spart);
  k_scan3<<<SNB, 1024, 0, stream>>>(cnt, spart, rowptr, cursor);
  k_fill<<<(NE+255)/256, 256, 0, stream>>>(esrc, edst, cursor, csr);

  k_wc   <<<(NL*H*450+255)/256, 256, 0, stream>>>(W, wih, Wc);
  k_packi<<<1500, 256, 0, stream>>>(Wc, wbi);
  k_packh<<<300,  256, 0, stream>>>(whh, wbh);
  k_packg<<<130,  256, 0, stream>>>(gw1, gw1b);

  k_cvt<<<(NN*80+255)/256, 256, 0, stream>>>(x, hb);
  hipMemcpyAsync(h, x, sizeof(float)*(size_t)NN*H, hipMemcpyDeviceToDevice, stream);

  for (int l = 0; l < NL; ++l){
    k_gather<<<NN/4, 256, 0, stream>>>(hb, rowptr, csr, aggb);
    k_gru<<<256, 512, 0, stream>>>(aggb, hb, h, wbi + (size_t)l*76800, wbh, bih, bhh);
  }
  k_gatepre<<<CHN, 256, 0, stream>>>(hb, gw1b, gb1, gw2, gb2, gbuf);
  k_readout<<<NG, 256, 0, stream>>>(gbuf, h, batch, out, gate_out);
}